// Round 21
// baseline (324.293 us; speedup 1.0000x reference)
//
#include <hip/hip_runtime.h>
#include <hip/hip_bf16.h>

#define NTOT 1048576
#define NSEG 4096
#define HDIM 128
#define ODIM 256
#define GRID1 8192        // blocks; 4 waves share 128 rows, each owns 64 cols
#define NSTEP 8           // 8 steps x 16 rows
#define PSEG 8            // LDS partial window (128-row block spans ~1-2 segs)

typedef __attribute__((ext_vector_type(8))) short bf16x8;
typedef __attribute__((ext_vector_type(4))) float f32x4;
typedef __attribute__((ext_vector_type(4))) unsigned int u32x4;

// HW packed f32->bf16 RNE (no builtin on gfx950)
__device__ __forceinline__ unsigned int cvt_pk(float lo, float hi) {
    unsigned int r;
    asm("v_cvt_pk_bf16_f32 %0, %1, %2" : "=v"(r) : "v"(lo), "v"(hi));
    return r;
}

// zero sumx (1M floats) + convert W1 (32768 f32 -> 16384 packed u32), one dispatch
__global__ void zero_convert(const float* __restrict__ W1, unsigned int* __restrict__ W1b,
                             float* __restrict__ sumx) {
    int gid = blockIdx.x * 256 + threadIdx.x;
    sumx[gid] = 0.0f;
    if (gid < (ODIM * HDIM / 2)) {
        float2 v = *(const float2*)(W1 + 2 * gid);
        W1b[gid] = cvt_pk(v.x, v.y);
    }
}

// R21: B-in-registers col-split. 4 waves/block share the SAME 128 rows (x read
// once from HBM; wave 2-4 reads hit L1/L2); wave wv computes cols [wv*64,+64)
// with its W1 fragments held in 64 VGPRs. Compute phase touches NO LDS except
// one seg ds_read + ds_add flushes (both lgkm) -> the 16 MB/CU of LDS B-reads
// that capped R17 at ~180us is gone. x loads are inline-asm (invisible to
// SIInsertWaitcnts); the only steady waits are manual counted vmcnt(8).
__global__ __launch_bounds__(256, 2)
void stage1(const float* __restrict__ x, const int* __restrict__ batch,
            const unsigned short* __restrict__ W1b, const float* __restrict__ b1,
            float* __restrict__ sumx) {
    __shared__ float part[PSEG * ODIM];     // 8 KB partial-sum window
    __shared__ int segAll[128];             // 512 B

    const int t    = threadIdx.x;
    const int lane = t & 63;
    const int wv   = t >> 6;
    const int l15  = lane & 15;
    const int lhi  = (lane >> 4) & 3;
    const int cb   = wv * 64;               // this wave's column base

    // dtype probe: int64 little-endian => odd (high) words are 0
    const bool is64 = (batch[NTOT - 1] == 0);
    const long blockrow = (long)blockIdx.x * 128;

    // ---- prologue (all compiler-tracked VMEM finishes before the barrier) ----
    if (t < 128) {
        long idx = blockrow + t;
        segAll[t] = batch[is64 ? 2 * idx : idx];
    }
    for (int i = t; i < PSEG * ODIM; i += 256) part[i] = 0.f;

    bf16x8 bfr[4][4];   // [nf][ks] W1 fragments for this wave's 64 cols (64 VGPR)
    #pragma unroll
    for (int nf = 0; nf < 4; ++nf)
        #pragma unroll
        for (int ks = 0; ks < 4; ++ks)
            bfr[nf][ks] = *(const bf16x8*)(W1b + (cb + nf * 16 + l15) * HDIM + ks * 32 + lhi * 8);
    float bias[4];
    #pragma unroll
    for (int nf = 0; nf < 4; ++nf) bias[nf] = b1[cb + nf * 16 + l15];
    const int segBase = batch[is64 ? 2 * blockrow : blockrow];

    __syncthreads();    // drains all prologue VMEM; after this, vmcnt domain is ours

    const char* xrow = (const char*)x + (blockrow + l15) * 512 + lhi * 32;

    int curSeg = segAll[0];
    float runsum[4] = {0.f, 0.f, 0.f, 0.f};

// 8 asm loads for step s: rows l15, floats ks*32+lhi*8.. (1 base reg + imm offs)
#define LOADSTEP(dst, s)                                                             \
    do { const float* _b = (const float*)(xrow + (size_t)(s) * 8192);                \
        asm volatile("global_load_dwordx4 %0, %1, off"            : "=v"(dst[0]) : "v"(_b)); \
        asm volatile("global_load_dwordx4 %0, %1, off offset:16"  : "=v"(dst[1]) : "v"(_b)); \
        asm volatile("global_load_dwordx4 %0, %1, off offset:128" : "=v"(dst[2]) : "v"(_b)); \
        asm volatile("global_load_dwordx4 %0, %1, off offset:144" : "=v"(dst[3]) : "v"(_b)); \
        asm volatile("global_load_dwordx4 %0, %1, off offset:256" : "=v"(dst[4]) : "v"(_b)); \
        asm volatile("global_load_dwordx4 %0, %1, off offset:272" : "=v"(dst[5]) : "v"(_b)); \
        asm volatile("global_load_dwordx4 %0, %1, off offset:384" : "=v"(dst[6]) : "v"(_b)); \
        asm volatile("global_load_dwordx4 %0, %1, off offset:400" : "=v"(dst[7]) : "v"(_b)); \
    } while (0)

#define FLUSH()                                                                   \
    do { if (lhi == 0) {                                                          \
            const unsigned _idx = (unsigned)(curSeg - segBase);                   \
            if (_idx < PSEG) {                                                    \
                float* _p = &part[_idx * ODIM + cb + l15];                        \
                _Pragma("unroll")                                                 \
                for (int nf = 0; nf < 4; ++nf)                                    \
                    atomicAdd(_p + nf * 16, runsum[nf]);       /* ds_add_f32 */   \
            } else {                                           /* ~never */      \
                float* _b = sumx + (long)curSeg * ODIM + cb + l15;                \
                _Pragma("unroll")                                                 \
                for (int nf = 0; nf < 4; ++nf)                                    \
                    atomicAdd(_b + nf * 16, runsum[nf]);                          \
                asm volatile("s_waitcnt vmcnt(0)" ::: "memory");  /* re-canon */  \
                __builtin_amdgcn_sched_barrier(0);                                \
            }                                                                     \
        }                                                                         \
        _Pragma("unroll")                                                         \
        for (int nf = 0; nf < 4; ++nf) runsum[nf] = 0.f;                          \
    } while (0)

#define STEP(s, cur, nxt)                                                         \
    do {                                                                          \
        if ((s) + 1 < NSTEP) {                                                    \
            LOADSTEP(nxt, (s) + 1);                                               \
            asm volatile("s_waitcnt vmcnt(8)" ::: "memory");   /* x(s) landed */  \
        } else {                                                                  \
            asm volatile("s_waitcnt vmcnt(0)" ::: "memory");                      \
        }                                                                         \
        __builtin_amdgcn_sched_barrier(0);                     /* rule 18 */      \
        int seg_l = segAll[(s) * 16 + l15];                    /* lgkm domain */  \
        int prv   = __shfl(seg_l, lane > 0 ? lane - 1 : 0);                       \
        unsigned bm = (unsigned)(__ballot(seg_l != prv)) & 0xFFFEu;               \
        int seg0 = __shfl(seg_l, 0);                                              \
        f32x4 acc[4];                                                             \
        _Pragma("unroll")                                                         \
        for (int nf = 0; nf < 4; ++nf)                                            \
            acc[nf] = (f32x4){bias[nf], bias[nf], bias[nf], bias[nf]};            \
        _Pragma("unroll")                                                         \
        for (int ks = 0; ks < 4; ++ks) {                                          \
            u32x4 w;                                                              \
            w.x = cvt_pk(cur[2*ks].x,   cur[2*ks].y);                             \
            w.y = cvt_pk(cur[2*ks].z,   cur[2*ks].w);                             \
            w.z = cvt_pk(cur[2*ks+1].x, cur[2*ks+1].y);                           \
            w.w = cvt_pk(cur[2*ks+1].z, cur[2*ks+1].w);                           \
            bf16x8 af = __builtin_bit_cast(bf16x8, w);                            \
            _Pragma("unroll")                                                     \
            for (int nf = 0; nf < 4; ++nf)                                        \
                acc[nf] = __builtin_amdgcn_mfma_f32_16x16x32_bf16(af, bfr[nf][ks], acc[nf], 0, 0, 0); \
        }                                                                         \
        _Pragma("unroll")                                                         \
        for (int nf = 0; nf < 4; ++nf)                                            \
            _Pragma("unroll")                                                     \
            for (int r = 0; r < 4; ++r) {                                         \
                float e = exp2f(acc[nf][r] * 2.885390081777927f);                 \
                acc[nf][r] = 1.0f - 2.0f * __builtin_amdgcn_rcpf(1.0f + e);       \
            }                                                                     \
        if (seg0 != curSeg) { FLUSH(); curSeg = seg0; }                           \
        int start = 0;                                                            \
        unsigned rem = bm;                                                        \
        for (;;) {                                                                \
            const int end = rem ? (int)__builtin_ctz(rem) : 16;                   \
            _Pragma("unroll")                                                     \
            for (int nf = 0; nf < 4; ++nf) {                                      \
                float sp = 0.f;                                                   \
                _Pragma("unroll")                                                 \
                for (int r = 0; r < 4; ++r) {                                     \
                    int row = lhi * 4 + r;                                        \
                    float wgt = ((unsigned)(row - start) < (unsigned)(end - start)) ? 1.0f : 0.0f; \
                    sp = fmaf(wgt, acc[nf][r], sp);                               \
                }                                                                 \
                sp += __shfl_xor(sp, 16);                                         \
                sp += __shfl_xor(sp, 32);                                         \
                runsum[nf] += sp;                                                 \
            }                                                                     \
            if (end == 16) break;                                                 \
            FLUSH();                                                              \
            curSeg = __shfl(seg_l, end);                                          \
            rem &= rem - 1;                                                       \
            start = end;                                                          \
        }                                                                         \
    } while (0)

    f32x4 cA[8], cB[8];
    LOADSTEP(cA, 0);            // outstanding = 8 (vmcnt domain is exactly ours)
    #pragma unroll
    for (int s = 0; s < NSTEP; s += 2) {
        STEP(s, cA, cB);
        STEP(s + 1, cB, cA);
    }
    FLUSH();   // final segment carry

#undef STEP
#undef FLUSH
#undef LOADSTEP

    // ---- flush partial window to sumx (one atomic pass per block) ----
    __syncthreads();
    const int segLast = segAll[127];
    int nrows = segLast - segBase + 1;
    if (nrows > PSEG) nrows = PSEG;
    for (int i = t; i < nrows * ODIM; i += 256)
        atomicAdd(&sumx[(long)(segBase + (i >> 8)) * ODIM + (i & 255)], part[i]);
}

// y[g][h] = b2[h] + sum_o sumx[g][o] * W2[h][o]   (fp32, 268 MFLOP)
__global__ __launch_bounds__(256)
void stage2(const float* __restrict__ sumx, const float* __restrict__ W2,
            const float* __restrict__ b2, float* __restrict__ y) {
    __shared__ float sx[16 * 256];
    const int t = threadIdx.x;
    const long g0 = (long)blockIdx.x * 16;
    #pragma unroll
    for (int i = 0; i < 16; ++i)
        sx[i * 256 + t] = sumx[(g0 + i) * 256 + t];
    __syncthreads();
    const int h = t & 127;
    const int gl0 = (t >> 7) * 8;
    float acc[8] = {0, 0, 0, 0, 0, 0, 0, 0};
    const float* w = W2 + h * 256;
    for (int o4 = 0; o4 < 64; ++o4) {
        float4 wvv = *(const float4*)(w + o4 * 4);
        #pragma unroll
        for (int gl = 0; gl < 8; ++gl) {
            const float* sr = &sx[(gl0 + gl) * 256 + o4 * 4];
            acc[gl] += sr[0] * wvv.x + sr[1] * wvv.y + sr[2] * wvv.z + sr[3] * wvv.w;
        }
    }
    float bb = b2[h];
    #pragma unroll
    for (int gl = 0; gl < 8; ++gl)
        y[(g0 + gl0 + gl) * 128 + h] = acc[gl] + bb;
}

extern "C" void kernel_launch(void* const* d_in, const int* in_sizes, int n_in,
                              void* d_out, int out_size, void* d_ws, size_t ws_size,
                              hipStream_t stream) {
    const float* x   = (const float*)d_in[0];
    const int* batch = (const int*)d_in[1];
    const float* W1  = (const float*)d_in[2];
    const float* b1  = (const float*)d_in[3];
    const float* W2  = (const float*)d_in[4];
    const float* b2  = (const float*)d_in[5];
    float* y = (float*)d_out;

    float* sumx = (float*)d_ws;                                                     // 4 MB
    unsigned short* W1b = (unsigned short*)((char*)d_ws + (size_t)NSEG * ODIM * 4); // 64 KB

    zero_convert<<<dim3(NSEG), dim3(256), 0, stream>>>(W1, (unsigned int*)W1b, sumx);
    stage1<<<dim3(GRID1), dim3(256), 0, stream>>>(x, batch, W1b, b1, sumx);
    stage2<<<dim3(NSEG / 16), dim3(256), 0, stream>>>(sumx, W2, b2, y);
}

// Round 22
// 201.110 us; speedup vs baseline: 1.6125x; 1.6125x over previous
//
#include <hip/hip_runtime.h>
#include <hip/hip_bf16.h>

#define NTOT 1048576
#define NSEG 4096
#define HDIM 128
#define ODIM 256
#define GRID1 2048        // blocks; 4 waves/block, 128 rows/wave, 512 rows/block
#define NSTEP 8           // 8 steps x 16 rows per wave

typedef __attribute__((ext_vector_type(8))) short bf16x8;
typedef __attribute__((ext_vector_type(4))) float f32x4;
typedef __attribute__((ext_vector_type(4))) unsigned int u32x4;

// HW packed f32->bf16 RNE (no builtin on gfx950)
__device__ __forceinline__ unsigned int cvt_pk(float lo, float hi) {
    unsigned int r;
    asm("v_cvt_pk_bf16_f32 %0, %1, %2" : "=v"(r) : "v"(lo), "v"(hi));
    return r;
}

// zero sumx (1M floats) + convert W1 (32768 f32 -> 16384 packed u32), one dispatch
__global__ void zero_convert(const float* __restrict__ W1, unsigned int* __restrict__ W1b,
                             float* __restrict__ sumx) {
    int gid = blockIdx.x * 256 + threadIdx.x;
    sumx[gid] = 0.0f;
    if (gid < (ODIM * HDIM / 2)) {
        float2 v = *(const float2*)(W1 + 2 * gid);
        W1b[gid] = cvt_pk(v.x, v.y);
    }
}

// R22 = R17 verbatim (verified best: 202.8us, absmax 0.25).
// Free-running row-slice kernel: W1 (64KB bf16) lives in LDS (read-only,
// XOR-swizzled, staged once -> ONE barrier total). Each wave owns 128 distinct
// rows (8 steps x 16), loads x straight to registers (prefetch 1 step ahead,
// ping-pong), computes all 256 output cols via MFMA with B from LDS, and does
// the sorted-segment reduce with a cross-step register carry (one atomic burst
// per segment per wave). Zero main-loop barriers.
__global__ __launch_bounds__(256, 2)
void stage1(const float* __restrict__ x, const int* __restrict__ batch,
            const unsigned short* __restrict__ W1b, const float* __restrict__ b1,
            float* __restrict__ sumx) {
    __shared__ __align__(16) unsigned char w1s[ODIM * HDIM * 2];   // 64 KB

    const int t    = threadIdx.x;
    const int lane = t & 63;
    const int wv   = t >> 6;
    const int l15  = lane & 15;
    const int lhi  = (lane >> 4) & 3;

    // dtype probe: int64 little-endian => odd (high) words are 0
    const bool is64 = (batch[NTOT - 1] == 0);

    // ---- stage W1 -> LDS, XOR-swizzled (verified swizzle: byte ^= (row&7)<<4) ----
    for (int c = t; c < 4096; c += 256) {           // 4096 x 16B chunks
        u32x4 v = ((const u32x4*)W1b)[c];
        int row = c >> 4;                           // 16 chunks per 256B row
        int kb  = (c & 15) * 16;
        *(u32x4*)(w1s + row * 256 + (kb ^ ((row & 7) << 4))) = v;
    }
    float bias[16];
    #pragma unroll
    for (int nf = 0; nf < 16; ++nf) bias[nf] = b1[nf * 16 + l15];
    __syncthreads();                                // the only block barrier

    // per-ks LDS read base (imm offset nf*4096 walks the 16 col-fragments)
    int lra[4];
    #pragma unroll
    for (int ks = 0; ks < 4; ++ks)
        lra[ks] = l15 * 256 + ((ks * 64 + lhi * 16) ^ ((l15 & 7) << 4));

    const long rowbase = (long)blockIdx.x * 512 + (long)wv * 128;
    const char* xrow = (const char*)x + (rowbase + l15) * 512 + lhi * 32;

    int curSeg = batch[is64 ? 2 * rowbase : rowbase];
    float runsum[16];
    #pragma unroll
    for (int nf = 0; nf < 16; ++nf) runsum[nf] = 0.f;

#define FLUSH()                                                                  \
    do { if (lhi == 0) {                                                         \
            float* _b = sumx + (long)curSeg * ODIM + l15;                        \
            _Pragma("unroll")                                                    \
            for (int nf = 0; nf < 16; ++nf) atomicAdd(_b + nf * 16, runsum[nf]); \
        }                                                                        \
        _Pragma("unroll")                                                        \
        for (int nf = 0; nf < 16; ++nf) runsum[nf] = 0.f;                        \
    } while (0)

#define LOADSTEP(dst, s)                                                          \
    do { const char* _p = xrow + (size_t)(s) * 8192;                              \
        _Pragma("unroll")                                                         \
        for (int ks = 0; ks < 4; ++ks) {                                          \
            dst[2*ks]   = *(const f32x4*)(_p + ks * 128);                         \
            dst[2*ks+1] = *(const f32x4*)(_p + ks * 128 + 16);                    \
        }                                                                         \
    } while (0)

#define STEP(s, cur, nxt)                                                         \
    do {                                                                          \
        if ((s) + 1 < NSTEP) LOADSTEP(nxt, (s) + 1);   /* prefetch, lands during compute */ \
        const long _r0 = rowbase + (long)(s) * 16;                                \
        int seg_l = batch[is64 ? 2 * (_r0 + l15) : (_r0 + l15)];                  \
        int prv   = __shfl(seg_l, lane > 0 ? lane - 1 : 0);                       \
        unsigned bm = (unsigned)(__ballot(seg_l != prv)) & 0xFFFEu;               \
        int seg0 = __shfl(seg_l, 0);                                              \
        f32x4 acc[16];                                                            \
        _Pragma("unroll")                                                         \
        for (int nf = 0; nf < 16; ++nf)                                           \
            acc[nf] = (f32x4){bias[nf], bias[nf], bias[nf], bias[nf]};            \
        _Pragma("unroll")                                                         \
        for (int ks = 0; ks < 4; ++ks) {                                          \
            u32x4 w;                                                              \
            w.x = cvt_pk(cur[2*ks].x,   cur[2*ks].y);                             \
            w.y = cvt_pk(cur[2*ks].z,   cur[2*ks].w);                             \
            w.z = cvt_pk(cur[2*ks+1].x, cur[2*ks+1].y);                           \
            w.w = cvt_pk(cur[2*ks+1].z, cur[2*ks+1].w);                           \
            bf16x8 af = __builtin_bit_cast(bf16x8, w);                            \
            _Pragma("unroll")                                                     \
            for (int nf = 0; nf < 16; ++nf) {                                     \
                bf16x8 bf = *(const bf16x8*)(w1s + lra[ks] + nf * 4096);          \
                acc[nf] = __builtin_amdgcn_mfma_f32_16x16x32_bf16(af, bf, acc[nf], 0, 0, 0); \
            }                                                                     \
        }                                                                         \
        _Pragma("unroll")                                                         \
        for (int nf = 0; nf < 16; ++nf)                                           \
            _Pragma("unroll")                                                     \
            for (int r = 0; r < 4; ++r) {                                         \
                float e = exp2f(acc[nf][r] * 2.885390081777927f);                 \
                acc[nf][r] = 1.0f - 2.0f * __builtin_amdgcn_rcpf(1.0f + e);       \
            }                                                                     \
        if (seg0 != curSeg) { FLUSH(); curSeg = seg0; }                           \
        int start = 0;                                                            \
        unsigned rem = bm;                                                        \
        for (;;) {                                                                \
            const int end = rem ? (int)__builtin_ctz(rem) : 16;                   \
            _Pragma("unroll")                                                     \
            for (int nf = 0; nf < 16; ++nf) {                                     \
                float sp = 0.f;                                                   \
                _Pragma("unroll")                                                 \
                for (int r = 0; r < 4; ++r) {                                     \
                    int row = lhi * 4 + r;                                        \
                    float wgt = ((unsigned)(row - start) < (unsigned)(end - start)) ? 1.0f : 0.0f; \
                    sp = fmaf(wgt, acc[nf][r], sp);                               \
                }                                                                 \
                sp += __shfl_xor(sp, 16);                                         \
                sp += __shfl_xor(sp, 32);                                         \
                runsum[nf] += sp;                                                 \
            }                                                                     \
            if (end == 16) break;                                                 \
            FLUSH();                                                              \
            curSeg = __shfl(seg_l, end);                                          \
            rem &= rem - 1;                                                       \
            start = end;                                                          \
        }                                                                         \
    } while (0)

    f32x4 cA[8], cB[8];
    LOADSTEP(cA, 0);
    #pragma unroll
    for (int s = 0; s < NSTEP; s += 2) {
        STEP(s, cA, cB);
        STEP(s + 1, cB, cA);
    }
    FLUSH();   // final segment carry

#undef STEP
#undef LOADSTEP
#undef FLUSH
}

// y[g][h] = b2[h] + sum_o sumx[g][o] * W2[h][o]   (fp32, 268 MFLOP)
__global__ __launch_bounds__(256)
void stage2(const float* __restrict__ sumx, const float* __restrict__ W2,
            const float* __restrict__ b2, float* __restrict__ y) {
    __shared__ float sx[16 * 256];
    const int t = threadIdx.x;
    const long g0 = (long)blockIdx.x * 16;
    #pragma unroll
    for (int i = 0; i < 16; ++i)
        sx[i * 256 + t] = sumx[(g0 + i) * 256 + t];
    __syncthreads();
    const int h = t & 127;
    const int gl0 = (t >> 7) * 8;
    float acc[8] = {0, 0, 0, 0, 0, 0, 0, 0};
    const float* w = W2 + h * 256;
    for (int o4 = 0; o4 < 64; ++o4) {
        float4 wvv = *(const float4*)(w + o4 * 4);
        #pragma unroll
        for (int gl = 0; gl < 8; ++gl) {
            const float* sr = &sx[(gl0 + gl) * 256 + o4 * 4];
            acc[gl] += sr[0] * wvv.x + sr[1] * wvv.y + sr[2] * wvv.z + sr[3] * wvv.w;
        }
    }
    float bb = b2[h];
    #pragma unroll
    for (int gl = 0; gl < 8; ++gl)
        y[(g0 + gl0 + gl) * 128 + h] = acc[gl] + bb;
}

extern "C" void kernel_launch(void* const* d_in, const int* in_sizes, int n_in,
                              void* d_out, int out_size, void* d_ws, size_t ws_size,
                              hipStream_t stream) {
    const float* x   = (const float*)d_in[0];
    const int* batch = (const int*)d_in[1];
    const float* W1  = (const float*)d_in[2];
    const float* b1  = (const float*)d_in[3];
    const float* W2  = (const float*)d_in[4];
    const float* b2  = (const float*)d_in[5];
    float* y = (float*)d_out;

    float* sumx = (float*)d_ws;                                                     // 4 MB
    unsigned short* W1b = (unsigned short*)((char*)d_ws + (size_t)NSEG * ODIM * 4); // 64 KB

    zero_convert<<<dim3(NSEG), dim3(256), 0, stream>>>(W1, (unsigned int*)W1b, sumx);
    stage1<<<dim3(GRID1), dim3(256), 0, stream>>>(x, batch, W1b, b1, sumx);
    stage2<<<dim3(NSEG / 16), dim3(256), 0, stream>>>(sumx, W2, b2, y);
}